// Round 1
// baseline (413.848 us; speedup 1.0000x reference)
//
#include <hip/hip_runtime.h>

#define CIN   64
#define COUT  64
#define HID   32
#define ZD    128
#define KC    1024
#define SPC   64
#define TLEN  65536

typedef __attribute__((ext_vector_type(8))) short bf16x8;
typedef __attribute__((ext_vector_type(4))) float f32x4;

__device__ __forceinline__ unsigned f2bf(float f) {
    unsigned u = __float_as_uint(f);
    unsigned r = u + 0x7fffu + ((u >> 16) & 1u);
    return r >> 16;
}
__device__ __forceinline__ unsigned pk2(float a, float b) {
    return f2bf(a) | (f2bf(b) << 16);
}

// w2 [8192 r][32 h] fp32 -> w2b [8192 r][16 packed bf16x2]  (B-fragment friendly)
__global__ void cast_w2_kernel(const float* __restrict__ w2, unsigned* __restrict__ w2b) {
    int i  = blockIdx.x * 256 + threadIdx.x;   // 131072
    int r  = i >> 4;
    int hp = i & 15;
    w2b[i] = pk2(w2[r * HID + 2 * hp], w2[r * HID + 2 * hp + 1]);
}

// x [B][CIN][T] fp32 -> xT [B][T][CIN] bf16 (tiled transpose through LDS)
__global__ __launch_bounds__(256)
void transpose_cast_x(const float* __restrict__ x, unsigned short* __restrict__ xT) {
    __shared__ unsigned short s[64][66];   // stride 66 shorts: conflict-free writes
    const int blk  = blockIdx.x;           // 8192 = B * T/64
    const int b    = blk >> 10;
    const int t0   = (blk & 1023) << 6;
    const int lane = threadIdx.x & 63;
    const int wv   = threadIdx.x >> 6;
    const float* xb = x + (size_t)b * CIN * TLEN;
    #pragma unroll
    for (int cc = 0; cc < 16; ++cc) {
        int c = cc * 4 + wv;
        s[lane][c] = (unsigned short)f2bf(xb[(size_t)c * TLEN + t0 + lane]);
    }
    __syncthreads();
    unsigned short* ob = xT + ((size_t)b * TLEN + t0) * CIN;
    #pragma unroll
    for (int half = 0; half < 2; ++half) {
        int si = (half * 256 + threadIdx.x) * 8;   // short index in 64x64 tile
        int t = si >> 6, c = si & 63;              // c multiple of 8 -> 4B-aligned LDS reads
        const unsigned* sp = (const unsigned*)&s[t][c];
        uint4 v; v.x = sp[0]; v.y = sp[1]; v.z = sp[2]; v.w = sp[3];
        *(uint4*)&ob[(size_t)t * CIN + c] = v;     // fully coalesced 16B/lane
    }
}

template<bool USE_XT>
__global__ __launch_bounds__(256, 4)
void hyperconv_mfma(const float* __restrict__ x, const unsigned short* __restrict__ xT,
                    const float* __restrict__ z,
                    const float* __restrict__ w1, const float* __restrict__ b1,
                    const float* __restrict__ b2,
                    const float* __restrict__ w3, const float* __restrict__ b3,
                    const float* __restrict__ w4, const float* __restrict__ b4,
                    const uint4* __restrict__ w2b,   // [8192 r][4] uint4
                    float* __restrict__ out)
{
    __shared__ __align__(16) float s_z[4][ZD];
    __shared__ __align__(16) float s_h3[4][HID];
    __shared__ __align__(16) float s_bias[4][COUT];
    __shared__ __align__(16) short s_h1b[4][HID];
    // double-buffered W chunks: [buf][sample][2048]  (one ks-chunk = 32 ik x 64 o)
    __shared__ __align__(16) short s_wc[2][4][2048];

    const int tid  = threadIdx.x;
    const int w    = tid >> 6;        // wave id == sample-in-block
    const int lane = tid & 63;
    const int l15  = lane & 15;
    const int q    = lane >> 4;
    const int n0   = blockIdx.x * 4;
    const int b    = n0 >> 10;
    const int kk0  = n0 & 1023;

    // ---- Phase A: stage z[b, :, kk0..kk0+3] ----
    #pragma unroll
    for (int i = 0; i < 2; ++i) {
        int idx = tid + i * 256;
        int g = idx >> 7, d = idx & 127;
        s_z[g][d] = z[((size_t)b * ZD + d) * KC + kk0 + g];
    }
    __syncthreads();

    // ---- Phase B: h1 (bf16) and h3 ----
    {
        int g = tid >> 6, u = tid & 63;
        const float* wrow = (u < HID) ? (w1 + u * ZD) : (w3 + (u - HID) * ZD);
        float acc = (u < HID) ? b1[u] : b3[u - HID];
        #pragma unroll
        for (int d4 = 0; d4 < ZD / 4; ++d4) {
            float4 wv = *(const float4*)(wrow + 4 * d4);
            float4 zv = *(const float4*)(&s_z[g][4 * d4]);
            acc += wv.x * zv.x + wv.y * zv.y + wv.z * zv.z + wv.w * zv.w;
        }
        acc = fmaxf(acc, 0.f);
        if (u < HID) s_h1b[g][u] = (short)f2bf(acc);
        else         s_h3[g][u - HID] = acc;
    }
    __syncthreads();

    // ---- Phase C: bias = w4@h3 + b4 (wave g computes s_bias[g]) ----
    {
        int g = tid >> 6, o = tid & 63;
        float acc = b4[o];
        #pragma unroll
        for (int h4 = 0; h4 < HID / 4; ++h4) {
            float4 wv = *(const float4*)(w4 + o * HID + 4 * h4);
            float4 hv = *(const float4*)(&s_h3[g][4 * h4]);
            acc += wv.x * hv.x + wv.y * hv.y + wv.z * hv.z + wv.w * hv.w;
        }
        s_bias[g][o] = acc;
    }

    // A-fragment for W-gen: row m holds sample m>>2 => quad q's C rows are ALL sample q
    bf16x8 afrag = *(const bf16x8*)&s_h1b[l15 >> 2][q * 8];

    // Produce one ks-chunk of W (all 4 samples) into s_wc[buf]; wave w covers ik-sub w.
    auto produce = [&](int ksr, int buf) {
        const int rb = ksr * 2048 + w * 512;
        #pragma unroll
        for (int ntl = 0; ntl < 4; ++ntl) {
            float cvq[8];
            #pragma unroll
            for (int jj = 0; jj < 8; ++jj) {
                int r = rb + 64 * jj + 16 * ntl + l15;
                float b2v = b2[r];
                bf16x8 bfrag = __builtin_bit_cast(bf16x8, w2b[r * 4 + q]);
                f32x4 c = __builtin_amdgcn_mfma_f32_16x16x32_bf16(
                    afrag, bfrag, (f32x4){b2v, b2v, b2v, b2v}, 0, 0, 0);
                cvq[jj] = c[0];   // rows 4q..4q+3 are identical (all sample q)
            }
            uint4 res;
            res.x = pk2(cvq[0], cvq[1]);
            res.y = pk2(cvq[2], cvq[3]);
            res.z = pk2(cvq[4], cvq[5]);
            res.w = pk2(cvq[6], cvq[7]);
            *(uint4*)&s_wc[buf][q][w * 512 + (16 * ntl + l15) * 8] = res;
        }
    };

    produce(0, 0);
    __syncthreads();

    // ---- Main loop: consume chunk ks from buf[ks&1], produce chunk ks+1 into buf^1 ----
    const int t0 = (kk0 + w) * SPC;
    const float* xb = x + (size_t)b * CIN * TLEN;
    const unsigned short* xtb = xT + (size_t)b * TLEN * CIN;

    f32x4 acc[4][4];
    #pragma unroll
    for (int i = 0; i < 4; ++i)
        #pragma unroll
        for (int j = 0; j < 4; ++j) acc[i][j] = (f32x4){0.f, 0.f, 0.f, 0.f};

    #pragma unroll
    for (int ks = 0; ks < 4; ++ks) {
        const int buf = ks & 1;

        // A fragments from current W chunk
        bf16x8 afr[4];
        #pragma unroll
        for (int ot = 0; ot < 4; ++ot)
            afr[ot] = *(const bf16x8*)&s_wc[buf][w][q * 512 + (16 * ot + l15) * 8];

        // B fragments from x
        const int koff = (ks >= 2) ? -1 : 0;   // ik>=64 -> x[t-1]
        const int c0 = (ks & 1) * 32 + 8 * q;
        bf16x8 bfr[4];
        if (USE_XT) {
            #pragma unroll
            for (int st = 0; st < 4; ++st) {
                int t = t0 + 16 * st + l15 + koff;
                uint4 p = (uint4){0u, 0u, 0u, 0u};
                if (t >= 0) p = *(const uint4*)&xtb[(size_t)t * CIN + c0];
                bfr[st] = __builtin_bit_cast(bf16x8, p);
            }
        } else {
            #pragma unroll
            for (int st = 0; st < 4; ++st) {
                int t = t0 + 16 * st + l15 + koff;
                int tc = t < 0 ? 0 : t;
                float v[8];
                #pragma unroll
                for (int j = 0; j < 8; ++j)
                    v[j] = xb[(size_t)(c0 + j) * TLEN + tc];
                if (t < 0) {
                    #pragma unroll
                    for (int j = 0; j < 8; ++j) v[j] = 0.f;
                }
                uint4 p;
                p.x = pk2(v[0], v[1]); p.y = pk2(v[2], v[3]);
                p.z = pk2(v[4], v[5]); p.w = pk2(v[6], v[7]);
                bfr[st] = __builtin_bit_cast(bf16x8, p);
            }
        }

        // overlap: produce next chunk into the other buffer while x loads are in flight
        if (ks < 3) produce(ks + 1, buf ^ 1);

        #pragma unroll
        for (int ot = 0; ot < 4; ++ot)
            #pragma unroll
            for (int st = 0; st < 4; ++st)
                acc[ot][st] = __builtin_amdgcn_mfma_f32_16x16x32_bf16(
                    afr[ot], bfr[st], acc[ot][st], 0, 0, 0);

        if (ks < 3) __syncthreads();
    }

    // ---- Epilogue: add bias, store (row=o, col=s; 16 consecutive t per quad) ----
    float* ob = out + (size_t)b * COUT * TLEN;
    #pragma unroll
    for (int ot = 0; ot < 4; ++ot) {
        f32x4 bv = *(const f32x4*)&s_bias[w][16 * ot + 4 * q];
        #pragma unroll
        for (int st = 0; st < 4; ++st) {
            int t = t0 + 16 * st + l15;
            #pragma unroll
            for (int reg = 0; reg < 4; ++reg)
                ob[(size_t)(16 * ot + 4 * q + reg) * TLEN + t] = acc[ot][st][reg] + bv[reg];
        }
    }
}

extern "C" void kernel_launch(void* const* d_in, const int* in_sizes, int n_in,
                              void* d_out, int out_size, void* d_ws, size_t ws_size,
                              hipStream_t stream) {
    const float* x  = (const float*)d_in[0];
    const float* z  = (const float*)d_in[1];
    const float* w1 = (const float*)d_in[2];
    const float* b1 = (const float*)d_in[3];
    const float* w2 = (const float*)d_in[4];
    const float* b2 = (const float*)d_in[5];
    const float* w3 = (const float*)d_in[6];
    const float* b3 = (const float*)d_in[7];
    const float* w4 = (const float*)d_in[8];
    const float* b4 = (const float*)d_in[9];
    float* out = (float*)d_out;

    unsigned* w2b = (unsigned*)d_ws;                                   // 512 KB
    unsigned short* xT = (unsigned short*)((char*)d_ws + 524288);      // 64 MB bf16 x^T
    const size_t need_xt = 524288ull + (size_t)8 * TLEN * CIN * 2;     // 67,633,152 B

    cast_w2_kernel<<<512, 256, 0, stream>>>(w2, w2b);
    if (ws_size >= need_xt) {
        transpose_cast_x<<<8192, 256, 0, stream>>>(x, xT);
        hyperconv_mfma<true><<<2048, 256, 0, stream>>>(x, xT, z, w1, b1, b2, w3, b3, w4, b4,
                                                       (const uint4*)w2b, out);
    } else {
        hyperconv_mfma<false><<<2048, 256, 0, stream>>>(x, xT, z, w1, b1, b2, w3, b3, w4, b4,
                                                        (const uint4*)w2b, out);
    }
}

// Round 3
// 374.546 us; speedup vs baseline: 1.1049x; 1.1049x over previous
//
#include <hip/hip_runtime.h>

#define CIN   64
#define COUT  64
#define HID   32
#define ZD    128
#define KC    1024
#define SPC   64
#define TLEN  65536

typedef __attribute__((ext_vector_type(8))) short bf16x8;
typedef __attribute__((ext_vector_type(4))) float f32x4;

__device__ __forceinline__ unsigned f2bf(float f) {
    unsigned u = __float_as_uint(f);
    unsigned r = u + 0x7fffu + ((u >> 16) & 1u);
    return r >> 16;
}
__device__ __forceinline__ unsigned pk2(float a, float b) {
    return f2bf(a) | (f2bf(b) << 16);
}

// w2 [8192 r][32 h] fp32 -> w2b [8192 r][16 packed bf16x2]  (B-fragment friendly)
__global__ void cast_w2_kernel(const float* __restrict__ w2, unsigned* __restrict__ w2b) {
    int i  = blockIdx.x * 256 + threadIdx.x;   // 131072
    int r  = i >> 4;
    int hp = i & 15;
    w2b[i] = pk2(w2[r * HID + 2 * hp], w2[r * HID + 2 * hp + 1]);
}

// x [B][CIN][T] fp32 -> xT [B][T][CIN] bf16 (tiled transpose through LDS)
__global__ __launch_bounds__(256)
void transpose_cast_x(const float* __restrict__ x, unsigned short* __restrict__ xT) {
    __shared__ unsigned short s[64][66];   // stride 66 shorts: conflict-free writes
    const int blk  = blockIdx.x;           // 8192 = B * T/64
    const int b    = blk >> 10;
    const int t0   = (blk & 1023) << 6;
    const int lane = threadIdx.x & 63;
    const int wv   = threadIdx.x >> 6;
    const float* xb = x + (size_t)b * CIN * TLEN;
    #pragma unroll
    for (int cc = 0; cc < 16; ++cc) {
        int c = cc * 4 + wv;
        s[lane][c] = (unsigned short)f2bf(xb[(size_t)c * TLEN + t0 + lane]);
    }
    __syncthreads();
    unsigned short* ob = xT + ((size_t)b * TLEN + t0) * CIN;
    #pragma unroll
    for (int half = 0; half < 2; ++half) {
        int si = (half * 256 + threadIdx.x) * 8;   // short index in 64x64 tile
        int t = si >> 6, c = si & 63;              // c multiple of 8 -> 4B-aligned LDS reads
        const unsigned* sp = (const unsigned*)&s[t][c];
        uint4 v; v.x = sp[0]; v.y = sp[1]; v.z = sp[2]; v.w = sp[3];
        *(uint4*)&ob[(size_t)t * CIN + c] = v;     // fully coalesced 16B/lane
    }
}

template<bool USE_XT>
__global__ __launch_bounds__(256, 2)
void hyperconv_mfma(const float* __restrict__ x, const unsigned short* __restrict__ xT,
                    const float* __restrict__ z,
                    const float* __restrict__ w1, const float* __restrict__ b1,
                    const float* __restrict__ b2,
                    const float* __restrict__ w3, const float* __restrict__ b3,
                    const float* __restrict__ w4, const float* __restrict__ b4,
                    const uint4* __restrict__ w2b,   // [8192 r][4] uint4
                    float* __restrict__ out)
{
    __shared__ __align__(16) float s_z[4][ZD];
    __shared__ __align__(16) float s_h3[4][HID];
    __shared__ __align__(16) float s_bias[4][COUT];
    __shared__ __align__(16) short s_h1b[4][HID];
    // double-buffered W chunks: [buf][sample][2048]  (one ks-chunk = 32 ik x 64 o)
    __shared__ __align__(16) short s_wc[2][4][2048];

    const int tid  = threadIdx.x;
    const int w    = tid >> 6;        // wave id == sample-in-block
    const int lane = tid & 63;
    const int l15  = lane & 15;
    const int q    = lane >> 4;
    const int n0   = blockIdx.x * 4;
    const int b    = n0 >> 10;
    const int kk0  = n0 & 1023;

    // ---- Phase A: stage z[b, :, kk0..kk0+3] ----
    #pragma unroll
    for (int i = 0; i < 2; ++i) {
        int idx = tid + i * 256;
        int g = idx >> 7, d = idx & 127;
        s_z[g][d] = z[((size_t)b * ZD + d) * KC + kk0 + g];
    }
    __syncthreads();

    // ---- Phase B: h1 (bf16) and h3 ----
    {
        int g = tid >> 6, u = tid & 63;
        const float* wrow = (u < HID) ? (w1 + u * ZD) : (w3 + (u - HID) * ZD);
        float acc = (u < HID) ? b1[u] : b3[u - HID];
        #pragma unroll
        for (int d4 = 0; d4 < ZD / 4; ++d4) {
            float4 wv = *(const float4*)(wrow + 4 * d4);
            float4 zv = *(const float4*)(&s_z[g][4 * d4]);
            acc += wv.x * zv.x + wv.y * zv.y + wv.z * zv.z + wv.w * zv.w;
        }
        acc = fmaxf(acc, 0.f);
        if (u < HID) s_h1b[g][u] = (short)f2bf(acc);
        else         s_h3[g][u - HID] = acc;
    }
    __syncthreads();

    // ---- Phase C: bias = w4@h3 + b4 (wave g computes s_bias[g]) ----
    {
        int g = tid >> 6, o = tid & 63;
        float acc = b4[o];
        #pragma unroll
        for (int h4 = 0; h4 < HID / 4; ++h4) {
            float4 wv = *(const float4*)(w4 + o * HID + 4 * h4);
            float4 hv = *(const float4*)(&s_h3[g][4 * h4]);
            acc += wv.x * hv.x + wv.y * hv.y + wv.z * hv.z + wv.w * hv.w;
        }
        s_bias[g][o] = acc;
    }

    // A-fragment for W-gen: row m holds sample m>>2 => quad q's C rows are ALL sample q
    bf16x8 afrag = *(const bf16x8*)&s_h1b[l15 >> 2][q * 8];

    // Produce one ks-chunk of W (all 4 samples) into s_wc[buf]; wave w covers ik-sub w.
    auto produce = [&](int ksr, int buf) {
        const int rb = ksr * 2048 + w * 512;
        #pragma unroll
        for (int ntl = 0; ntl < 4; ++ntl) {
            float cvq[8];
            #pragma unroll
            for (int jj = 0; jj < 8; ++jj) {
                int r = rb + 64 * jj + 16 * ntl + l15;
                float b2v = b2[r];
                bf16x8 bfrag = __builtin_bit_cast(bf16x8, w2b[r * 4 + q]);
                f32x4 c = __builtin_amdgcn_mfma_f32_16x16x32_bf16(
                    afrag, bfrag, (f32x4){b2v, b2v, b2v, b2v}, 0, 0, 0);
                cvq[jj] = c[0];   // rows 4q..4q+3 are identical (all sample q)
            }
            uint4 res;
            res.x = pk2(cvq[0], cvq[1]);
            res.y = pk2(cvq[2], cvq[3]);
            res.z = pk2(cvq[4], cvq[5]);
            res.w = pk2(cvq[6], cvq[7]);
            *(uint4*)&s_wc[buf][q][w * 512 + (16 * ntl + l15) * 8] = res;
        }
    };

    produce(0, 0);
    __syncthreads();

    // ---- Main loop: consume chunk ks from buf[ks&1]; then produce chunk ks+1 into buf^1 ----
    const int t0 = (kk0 + w) * SPC;
    const float* xb = x + (size_t)b * CIN * TLEN;
    const unsigned short* xtb = xT + (size_t)b * TLEN * CIN;

    f32x4 acc[4][4];
    #pragma unroll
    for (int i = 0; i < 4; ++i)
        #pragma unroll
        for (int j = 0; j < 4; ++j) acc[i][j] = (f32x4){0.f, 0.f, 0.f, 0.f};

    #pragma unroll
    for (int ks = 0; ks < 4; ++ks) {
        const int buf = ks & 1;

        // B fragments from x (issue loads first so they're in flight during ds_reads)
        const int koff = (ks >= 2) ? -1 : 0;   // ik>=64 -> x[t-1]
        const int c0 = (ks & 1) * 32 + 8 * q;
        bf16x8 bfr[4];
        if (USE_XT) {
            #pragma unroll
            for (int st = 0; st < 4; ++st) {
                int t = t0 + 16 * st + l15 + koff;
                uint4 p = (uint4){0u, 0u, 0u, 0u};
                if (t >= 0) p = *(const uint4*)&xtb[(size_t)t * CIN + c0];
                bfr[st] = __builtin_bit_cast(bf16x8, p);
            }
        } else {
            #pragma unroll
            for (int st = 0; st < 4; ++st) {
                int t = t0 + 16 * st + l15 + koff;
                int tc = t < 0 ? 0 : t;
                float v[8];
                #pragma unroll
                for (int j = 0; j < 8; ++j)
                    v[j] = xb[(size_t)(c0 + j) * TLEN + tc];
                if (t < 0) {
                    #pragma unroll
                    for (int j = 0; j < 8; ++j) v[j] = 0.f;
                }
                uint4 p;
                p.x = pk2(v[0], v[1]); p.y = pk2(v[2], v[3]);
                p.z = pk2(v[4], v[5]); p.w = pk2(v[6], v[7]);
                bfr[st] = __builtin_bit_cast(bf16x8, p);
            }
        }

        // A fragments from current W chunk, one at a time (keeps peak VGPR pressure low)
        #pragma unroll
        for (int ot = 0; ot < 4; ++ot) {
            bf16x8 afr = *(const bf16x8*)&s_wc[buf][w][q * 512 + (16 * ot + l15) * 8];
            #pragma unroll
            for (int st = 0; st < 4; ++st)
                acc[ot][st] = __builtin_amdgcn_mfma_f32_16x16x32_bf16(
                    afr, bfr[st], acc[ot][st], 0, 0, 0);
        }

        // produce next chunk AFTER consume: minimal live-range overlap with afr/bfr
        if (ks < 3) {
            produce(ks + 1, buf ^ 1);
            __syncthreads();
        }
    }

    // ---- Epilogue: add bias, store (row=o, col=s; 16 consecutive t per quad) ----
    float* ob = out + (size_t)b * COUT * TLEN;
    #pragma unroll
    for (int ot = 0; ot < 4; ++ot) {
        f32x4 bv = *(const f32x4*)&s_bias[w][16 * ot + 4 * q];
        #pragma unroll
        for (int st = 0; st < 4; ++st) {
            int t = t0 + 16 * st + l15;
            #pragma unroll
            for (int reg = 0; reg < 4; ++reg)
                ob[(size_t)(16 * ot + 4 * q + reg) * TLEN + t] = acc[ot][st][reg] + bv[reg];
        }
    }
}

extern "C" void kernel_launch(void* const* d_in, const int* in_sizes, int n_in,
                              void* d_out, int out_size, void* d_ws, size_t ws_size,
                              hipStream_t stream) {
    const float* x  = (const float*)d_in[0];
    const float* z  = (const float*)d_in[1];
    const float* w1 = (const float*)d_in[2];
    const float* b1 = (const float*)d_in[3];
    const float* w2 = (const float*)d_in[4];
    const float* b2 = (const float*)d_in[5];
    const float* w3 = (const float*)d_in[6];
    const float* b3 = (const float*)d_in[7];
    const float* w4 = (const float*)d_in[8];
    const float* b4 = (const float*)d_in[9];
    float* out = (float*)d_out;

    unsigned* w2b = (unsigned*)d_ws;                                   // 512 KB
    unsigned short* xT = (unsigned short*)((char*)d_ws + 524288);      // 64 MB bf16 x^T
    const size_t need_xt = 524288ull + (size_t)8 * TLEN * CIN * 2;     // 67,633,152 B

    cast_w2_kernel<<<512, 256, 0, stream>>>(w2, w2b);
    if (ws_size >= need_xt) {
        transpose_cast_x<<<8192, 256, 0, stream>>>(x, xT);
        hyperconv_mfma<true><<<2048, 256, 0, stream>>>(x, xT, z, w1, b1, b2, w3, b3, w4, b4,
                                                       (const uint4*)w2b, out);
    } else {
        hyperconv_mfma<false><<<2048, 256, 0, stream>>>(x, xT, z, w1, b1, b2, w3, b3, w4, b4,
                                                        (const uint4*)w2b, out);
    }
}